// Round 10
// baseline (373.164 us; speedup 1.0000x reference)
//
#include <hip/hip_runtime.h>

typedef __attribute__((ext_vector_type(8))) short short8;
typedef __attribute__((ext_vector_type(4))) float floatx4;
typedef __attribute__((ext_vector_type(2))) float floatx2;

constexpr int DIM   = 128;   // dim_in == dim_out
constexpr int NB    = 4;     // bases
constexpr int NR    = 8;     // relations
constexpr int BROWS = 512;   // rows per sort bucket
constexpr int BCAP  = 16384; // fixed bucket capacity (mean 8192, +90 sigma)
constexpr int BATCH = 8;     // tiles per fused barrier-batch

static __device__ __forceinline__ unsigned short f2bf(float f) {
    unsigned int u = __float_as_uint(f);
    u += 0x7FFFu + ((u >> 16) & 1u);
    return (unsigned short)(u >> 16);
}
static __device__ __forceinline__ float bf_lo(unsigned int h) {
    return __uint_as_float(h << 16);
}
static __device__ __forceinline__ float bf_hi(unsigned int h) {
    return __uint_as_float(h & 0xFFFF0000u);
}

// ---------------------------------------------------------------------------
// Vfrag[b][ot][ks][lane][j] = V[b][k][o], k=ks*32+(lane>>4)*8+j, o=ot*16+(lane&15)
// (kept for the fallback path; main path uses prep_kernel)
// ---------------------------------------------------------------------------
__global__ __launch_bounds__(256) void build_vfrag(
    const float* __restrict__ V, unsigned short* __restrict__ VfragG)
{
    int idx  = blockIdx.x * 256 + threadIdx.x;   // 0 .. 8191
    int lane = idx & 63;
    int ks   = (idx >> 6) & 3;
    int ot   = (idx >> 8) & 7;
    int b    = idx >> 11;

    int o  = ot * 16 + (lane & 15);
    int kb = ks * 32 + (lane >> 4) * 8;

    short8 v;
#pragma unroll
    for (int j = 0; j < 8; ++j)
        v[j] = (short)f2bf(V[((size_t)b * DIM + kb + j) * DIM + o]);
    *reinterpret_cast<short8*>(VfragG + (size_t)idx * 8) = v;
}

// ---------------------------------------------------------------------------
// W_r fragments (fallback path only)
// ---------------------------------------------------------------------------
__global__ __launch_bounds__(256) void build_wfrag(
    const float* __restrict__ A, const float* __restrict__ V,
    unsigned short* __restrict__ Wfrag)
{
    int idx  = blockIdx.x * 256 + threadIdx.x;   // 0 .. 16383
    int lane = idx & 63;
    int ks   = (idx >> 6) & 3;
    int ot   = (idx >> 8) & 7;
    int r    = idx >> 11;

    int o     = ot * 16 + (lane & 15);
    int kbase = ks * 32 + (lane >> 4) * 8;

    float a0 = A[r * NB + 0], a1 = A[r * NB + 1];
    float a2 = A[r * NB + 2], a3 = A[r * NB + 3];

    short8 v;
#pragma unroll
    for (int j = 0; j < 8; ++j) {
        int k = kbase + j;
        float w = a0 * V[(0 * DIM + k) * DIM + o]
                + a1 * V[(1 * DIM + k) * DIM + o]
                + a2 * V[(2 * DIM + k) * DIM + o]
                + a3 * V[(3 * DIM + k) * DIM + o];
        v[j] = (short)f2bf(w);
    }
    *reinterpret_cast<short8*>(Wfrag + (size_t)idx * 8) = v;
}

// ---------------------------------------------------------------------------
// H (fp32) -> Hbf (bf16)  (fallback path; main path uses prep_kernel)
// ---------------------------------------------------------------------------
__global__ __launch_bounds__(256) void h_to_bf(
    const float* __restrict__ H, unsigned short* __restrict__ Hbf, int n8)
{
    int i = blockIdx.x * 256 + threadIdx.x;
    if (i >= n8) return;
    const float4* hp = reinterpret_cast<const float4*>(H) + (size_t)i * 2;
    float4 f0 = hp[0];
    float4 f1 = hp[1];
    short8 v;
    v[0] = (short)f2bf(f0.x); v[1] = (short)f2bf(f0.y);
    v[2] = (short)f2bf(f0.z); v[3] = (short)f2bf(f0.w);
    v[4] = (short)f2bf(f1.x); v[5] = (short)f2bf(f1.y);
    v[6] = (short)f2bf(f1.z); v[7] = (short)f2bf(f1.w);
    *reinterpret_cast<short8*>(Hbf + (size_t)i * 8) = v;
}

// ---------------------------------------------------------------------------
// Merged prologue: h_to_bf (blocks 0..6249) + build_vfrag (next 32 blocks)
// + bcnt zero (last block). The three are independent; merging removes two
// launch gaps and overlaps their execution.
// ---------------------------------------------------------------------------
__global__ __launch_bounds__(256) void prep_kernel(
    const float* __restrict__ H, unsigned short* __restrict__ Hbf, int n8,
    const float* __restrict__ V, unsigned short* __restrict__ VfragG,
    int* __restrict__ bcnt, int nHb)
{
    int blk = blockIdx.x;
    int t   = threadIdx.x;
    if (blk < nHb) {
        int i = blk * 256 + t;
        if (i >= n8) return;
        const float4* hp = reinterpret_cast<const float4*>(H) + (size_t)i * 2;
        float4 f0 = hp[0];
        float4 f1 = hp[1];
        short8 v;
        v[0] = (short)f2bf(f0.x); v[1] = (short)f2bf(f0.y);
        v[2] = (short)f2bf(f0.z); v[3] = (short)f2bf(f0.w);
        v[4] = (short)f2bf(f1.x); v[5] = (short)f2bf(f1.y);
        v[6] = (short)f2bf(f1.z); v[7] = (short)f2bf(f1.w);
        *reinterpret_cast<short8*>(Hbf + (size_t)i * 8) = v;
    } else if (blk < nHb + 32) {
        int idx  = (blk - nHb) * 256 + t;     // 0 .. 8191
        int lane = idx & 63;
        int ks   = (idx >> 6) & 3;
        int ot   = (idx >> 8) & 7;
        int b    = idx >> 11;
        int o  = ot * 16 + (lane & 15);
        int kb = ks * 32 + (lane >> 4) * 8;
        short8 v;
#pragma unroll
        for (int j = 0; j < 8; ++j)
            v[j] = (short)f2bf(V[((size_t)b * DIM + kb + j) * DIM + o]);
        *reinterpret_cast<short8*>(VfragG + (size_t)idx * 8) = v;
    } else {
        bcnt[t] = 0;
    }
}

// ---------------------------------------------------------------------------
// Sort pass 1: scatter edges into fixed-capacity coarse buckets.
// ---------------------------------------------------------------------------
__global__ __launch_bounds__(256) void bucket_scatter(
    const int* __restrict__ erow, const int* __restrict__ ecol,
    const float* __restrict__ eval, int* __restrict__ bcnt,
    int2* __restrict__ sorted1, int n, int E, int chunk)
{
    __shared__ int cnt[256];
    __shared__ int base[256];
    int t = threadIdx.x;
    cnt[t] = 0;
    __syncthreads();

    int s = blockIdx.x * chunk;
    int e = s + chunk; if (e > n) e = n;

    for (int i = s + t; i < e; i += 256)
        atomicAdd(&cnt[erow[i] >> 9], 1);
    __syncthreads();

    int c = cnt[t];
    base[t] = (c > 0) ? atomicAdd(&bcnt[t], c) : 0;
    cnt[t] = 0;
    __syncthreads();

    for (int i = s + t; i < e; i += 256) {
        int row = erow[i];
        int bkt = row >> 9;
        int rank = atomicAdd(&cnt[bkt], 1);
        int r = (int)((unsigned)i / (unsigned)E);
        int2 m;
        m.x = ((row & (BROWS - 1)) << 20) | (r << 17) | ecol[i];
        m.y = __float_as_int(eval[i]);
        sorted1[(size_t)bkt * BCAP + base[bkt] + rank] = m;
    }
}

// ---------------------------------------------------------------------------
// Sort pass 2: one block per bucket; compacts to exact final positions.
// ---------------------------------------------------------------------------
__global__ __launch_bounds__(1024) void bucket_sort(
    const int2* __restrict__ sorted1, const int* __restrict__ bcnt,
    int* __restrict__ rowStart, int2* __restrict__ sorted, int Ne, int nbuc)
{
    __shared__ int hcnt[BROWS];   // per-local-row counts, then rank counters
    __shared__ int hoff[BROWS];   // per-local-row exclusive offsets
    __shared__ int sd[256];       // bucket-count inclusive scan
    int b = blockIdx.x;
    int t = threadIdx.x;

    for (int i = t; i < BROWS; i += 1024) hcnt[i] = 0;

    if (t < 256) sd[t] = (t < nbuc) ? bcnt[t] : 0;
    __syncthreads();
#pragma unroll
    for (int off = 1; off < 256; off <<= 1) {
        int v = (t < 256 && t >= off) ? sd[t - off] : 0;
        __syncthreads();
        if (t < 256) sd[t] += v;
        __syncthreads();
    }
    if (b == 0 && t == nbuc - 1) rowStart[Ne] = sd[t];

    int n  = bcnt[b];
    int bs = sd[b] - n;               // exclusive prefix of this bucket
    const int2* src = sorted1 + (size_t)b * BCAP;

    for (int i = t; i < n; i += 1024)
        atomicAdd(&hcnt[(unsigned)src[i].x >> 20], 1);
    __syncthreads();

    // parallel exclusive scan of the 512 row counts
    if (t < BROWS) hoff[t] = hcnt[t];
    __syncthreads();
#pragma unroll
    for (int off = 1; off < BROWS; off <<= 1) {
        int v = (t < BROWS && t >= off) ? hoff[t - off] : 0;
        __syncthreads();
        if (t < BROWS) hoff[t] += v;
        __syncthreads();
    }
    if (t < BROWS) hoff[t] -= hcnt[t];   // own-element only: no hazard
    __syncthreads();

    int rs = b * BROWS;
    int nr = Ne - rs; if (nr > BROWS) nr = BROWS;
    for (int j = t; j < nr; j += 1024)
        rowStart[rs + j] = bs + hoff[j];

    for (int i = t; i < BROWS; i += 1024) hcnt[i] = 0;
    __syncthreads();

    for (int i = t; i < n; i += 1024) {
        int2 m = src[i];
        int lr = (unsigned)m.x >> 20;
        int pos = bs + hoff[lr] + atomicAdd(&hcnt[lr], 1);
        sorted[pos] = m;
    }
}

// ---------------------------------------------------------------------------
// FUSED K_A + K_B, 8-tile batch. Per batch: each of 16 waves aggregates its
// row (row=wave) of EACH of 8 tiles (sum of 8 Poisson(16) rows -> max/mean
// imbalance 1.21x vs 1.59x at batch=1, the round-9 cost), writes to the
// 8x16KB ldsA set (row-field XOR-swizzled so ds_write_b32 hits 32 banks at
// the free 2-way floor; round-9 pattern was 4-way on 16 banks = 4M conflict
// counts). One barrier; then 64 MFMA tasks (8 tiles x 8 col-blocks) across
// ALL 16 waves, V-fragments read from GLOBAL (128KB, identical for every
// CU -> permanently L2-resident) instead of LDS. ldsA = 128KB <= 160.
// Contiguous per-block tile ranges (24-25 tiles) -> no batch-count tail.
// __launch_bounds__(1024, 4): 128-VGPR cap, 1 block/CU (proven round 9).
// ---------------------------------------------------------------------------
#define AGG_LOAD8(kk, vv, hh, base)                                          \
    _Pragma("unroll")                                                        \
    for (int u = 0; u < 8; ++u) {                                            \
        int2 m = sorted[(base) + u];                                         \
        kk[u] = __builtin_amdgcn_readfirstlane(m.x);                         \
        vv[u] = __uint_as_float(__builtin_amdgcn_readfirstlane(m.y));        \
    }                                                                        \
    _Pragma("unroll")                                                        \
    for (int u = 0; u < 8; ++u)                                              \
        hh[u] = reinterpret_cast<const unsigned int*>(                       \
            Hbf + (size_t)(kk[u] & 0x1FFFF) * DIM)[lane];

#define AGG_FMA8(kk, vv, hh)                                                 \
    _Pragma("unroll")                                                        \
    for (int u = 0; u < 8; ++u) {                                            \
        float4 a = Af[((unsigned)kk[u] >> 17) & 7];                          \
        floatx2 h; h[0] = bf_lo(hh[u]); h[1] = bf_hi(hh[u]);                 \
        float s0 = vv[u] * a.x, s1 = vv[u] * a.y;                            \
        float s2 = vv[u] * a.z, s3 = vv[u] * a.w;                            \
        acc[0] += (floatx2){s0, s0} * h;                                     \
        acc[1] += (floatx2){s1, s1} * h;                                     \
        acc[2] += (floatx2){s2, s2} * h;                                     \
        acc[3] += (floatx2){s3, s3} * h;                                     \
    }

__global__ __launch_bounds__(1024, 4) void fused_kernel(
    const unsigned short* __restrict__ Hbf,
    const int*  __restrict__ rowStart,
    const int2* __restrict__ sorted,
    const float* __restrict__ Aw,
    const unsigned short* __restrict__ VfragG,
    float* __restrict__ out, int Ne, int nTiles)
{
    __shared__ unsigned short ldsA[BATCH * 8192];   // 8 A-tiles, 128 KB

    int tid  = threadIdx.x;
    int wave = tid >> 6;
    int lane = tid & 63;
    int quad = lane >> 4, l15 = lane & 15;

    const float4*  Af = reinterpret_cast<const float4*>(Aw);
    const short8*  Vf = reinterpret_cast<const short8*>(VfragG);

    // contiguous tile range for this block (differs by <=1 tile per block)
    int t0 = (int)(((long long)blockIdx.x       * nTiles) / gridDim.x);
    int t1 = (int)(((long long)(blockIdx.x + 1) * nTiles) / gridDim.x);

    // per-lane ldsA write slot (ushort units), row-field XOR-swizzled:
    // lane = (q,x,y): element cols {2*lane,2*lane+1} of basis b, row 'wave'
    //   unit = sub*8192 + b*2048 + q*512 + (wave^(q&1))*32 + x*8 + y*2
    int q_ = quad, x_ = (lane >> 2) & 3, y_ = lane & 3;
    int awBase = q_ * 512 + ((wave ^ (q_ & 1)) * 32) + x_ * 8 + y_ * 2;

    for (int base = t0; base < t1; base += BATCH) {
        int nsub = t1 - base; if (nsub > BATCH) nsub = BATCH;

        // ---- phase 1: aggregate row 'wave' of each sub-tile ----
        for (int sub = 0; sub < nsub; ++sub) {
            int node = (base + sub) * 16 + wave;
            floatx2 acc[4];
#pragma unroll
            for (int b = 0; b < 4; ++b) acc[b] = (floatx2){0.f, 0.f};

            if (node < Ne) {
                int s = __builtin_amdgcn_readfirstlane(rowStart[node]);
                int e = __builtin_amdgcn_readfirstlane(rowStart[node + 1]);
                int i = s;
                if (i + 8 <= e) {
                    int kkA[8], kkB[8];
                    float vvA[8], vvB[8];
                    unsigned int hhA[8], hhB[8];
                    AGG_LOAD8(kkA, vvA, hhA, i); i += 8;
                    for (;;) {
                        if (i + 8 <= e) {
                            AGG_LOAD8(kkB, vvB, hhB, i); i += 8;
                            AGG_FMA8(kkA, vvA, hhA);
                        } else { AGG_FMA8(kkA, vvA, hhA); break; }
                        if (i + 8 <= e) {
                            AGG_LOAD8(kkA, vvA, hhA, i); i += 8;
                            AGG_FMA8(kkB, vvB, hhB);
                        } else { AGG_FMA8(kkB, vvB, hhB); break; }
                    }
                }
                for (; i < e; ++i) {
                    int2 m = sorted[i];
                    int k = __builtin_amdgcn_readfirstlane(m.x);
                    float v = __uint_as_float(
                        __builtin_amdgcn_readfirstlane(m.y));
                    unsigned int hu = reinterpret_cast<const unsigned int*>(
                        Hbf + (size_t)(k & 0x1FFFF) * DIM)[lane];
                    float4 a = Af[((unsigned)k >> 17) & 7];
                    floatx2 h; h[0] = bf_lo(hu); h[1] = bf_hi(hu);
                    float s0 = v * a.x, s1 = v * a.y;
                    float s2 = v * a.z, s3 = v * a.w;
                    acc[0] += (floatx2){s0, s0} * h;
                    acc[1] += (floatx2){s1, s1} * h;
                    acc[2] += (floatx2){s2, s2} * h;
                    acc[3] += (floatx2){s3, s3} * h;
                }
            }
            unsigned short* aw = ldsA + sub * 8192 + awBase;
#pragma unroll
            for (int b = 0; b < 4; ++b) {
                unsigned int pk = (unsigned int)f2bf(acc[b][0])
                                | ((unsigned int)f2bf(acc[b][1]) << 16);
                *reinterpret_cast<unsigned int*>(aw + b * 2048) = pk;
            }
        }
        __syncthreads();   // A-tiles complete

        // ---- phase 2: 64 tasks (sub, ot) across all 16 waves ----
#pragma unroll
        for (int j = 0; j < 4; ++j) {
            int task = wave * 4 + j;          // 0..63
            int sub  = task >> 3, ot = task & 7;
            if (sub < nsub) {
                const short8* a8 =
                    reinterpret_cast<const short8*>(ldsA + sub * 8192);
                floatx4 vacc = (floatx4){0.f, 0.f, 0.f, 0.f};
#pragma unroll
                for (int b = 0; b < 4; ++b)
#pragma unroll
                    for (int ks = 0; ks < 4; ++ks)
                        vacc = __builtin_amdgcn_mfma_f32_16x16x32_bf16(
                            Vf[((b * 8 + ot) * 4 + ks) * 64 + lane],
                            a8[b * 256 + ks * 64
                               + (l15 ^ (ks & 1)) * 4 + quad],
                            vacc, 0, 0, 0);

                int onode = (base + sub) * 16 + l15;
                if (onode < Ne) {
                    float4 st;
                    st.x = vacc[0]; st.y = vacc[1];
                    st.z = vacc[2]; st.w = vacc[3];
                    *reinterpret_cast<float4*>(
                        out + (size_t)onode * DIM + ot * 16 + quad * 4) = st;
                }
            }
        }
        __syncthreads();   // protect ldsA before next batch
    }
}

// ---------------------------------------------------------------------------
// Fallback (ws too small): round-2 atomic kernel
// ---------------------------------------------------------------------------
__global__ __launch_bounds__(256) void rgcn_main(
    const unsigned short* __restrict__ Hbf,
    const unsigned short* __restrict__ Wfrag,
    const int*   __restrict__ erow,
    const int*   __restrict__ ecol,
    const float* __restrict__ eval,
    float*       __restrict__ out,
    int E, int groups_per_rel, int waves_per_rel)
{
    int wid  = blockIdx.x * 4 + (threadIdx.x >> 6);
    int lane = threadIdx.x & 63;
    int r    = wid & 7;
    int wr   = wid >> 3;
    int quad = lane >> 4;
    int l15  = lane & 15;

    short8 b[8][4];
    {
        const short8* wp = reinterpret_cast<const short8*>(
            Wfrag + (size_t)r * 16384);
#pragma unroll
        for (int ot = 0; ot < 8; ++ot)
#pragma unroll
            for (int ks = 0; ks < 4; ++ks)
                b[ot][ks] = wp[(ot * 4 + ks) * 64 + lane];
    }

    for (int g = wr; g < groups_per_rel; g += waves_per_rel) {
        int ebase = r * E + g * 16;
        int   colv = ecol[ebase + l15];
        int   rowv = erow[ebase + l15];
        float valv = eval[ebase + l15];

        short8 a[4];
        const unsigned short* hp = Hbf + (size_t)colv * DIM + quad * 8;
#pragma unroll
        for (int ks = 0; ks < 4; ++ks)
            a[ks] = *reinterpret_cast<const short8*>(hp + ks * 32);

        floatx4 acc[8];
#pragma unroll
        for (int ot = 0; ot < 8; ++ot) acc[ot] = (floatx4){0.f, 0.f, 0.f, 0.f};
#pragma unroll
        for (int ot = 0; ot < 8; ++ot)
#pragma unroll
            for (int ks = 0; ks < 4; ++ks)
                acc[ot] = __builtin_amdgcn_mfma_f32_16x16x32_bf16(
                    a[ks], b[ot][ks], acc[ot], 0, 0, 0);

        int   row4[4];
        float val4[4];
#pragma unroll
        for (int reg = 0; reg < 4; ++reg) {
            int src  = quad * 4 + reg;
            row4[reg] = __shfl(rowv, src, 64);
            val4[reg] = __shfl(valv, src, 64);
        }
#pragma unroll
        for (int ot = 0; ot < 8; ++ot)
#pragma unroll
            for (int reg = 0; reg < 4; ++reg) {
                float m = acc[ot][reg] * val4[reg];
                atomicAdd(out + (size_t)row4[reg] * DIM + ot * 16 + l15, m);
            }
    }
}

extern "C" void kernel_launch(void* const* d_in, const int* in_sizes, int n_in,
                              void* d_out, int out_size, void* d_ws, size_t ws_size,
                              hipStream_t stream)
{
    const float* H    = (const float*)d_in[0];
    const float* A    = (const float*)d_in[1];
    const float* V    = (const float*)d_in[2];
    const int*   erow = (const int*)d_in[3];
    const int*   ecol = (const int*)d_in[4];
    const float* eval = (const float*)d_in[5];
    float* out = (float*)d_out;

    int Ne    = in_sizes[0] / DIM;   // 100000
    int NEtot = in_sizes[3];         // 1.6M
    int E     = NEtot / NR;          // 200000

    auto al = [](size_t x) { return (x + 255) & ~(size_t)255; };

    int nbuc = (Ne + BROWS - 1) / BROWS;   // 196
    int nTiles = (Ne + 15) / 16;           // 6250 (Ne divisible by 16)

    size_t offHbf    = 0;
    size_t offVfrag  = offHbf    + al((size_t)Ne * DIM * 2);
    size_t offWfrag  = offVfrag  + al((size_t)8192 * 16);
    size_t offSort1  = offWfrag  + al((size_t)16384 * 16);
    size_t offRow    = offSort1  + al((size_t)nbuc * BCAP * 8);
    size_t offBcnt   = offRow    + al(((size_t)Ne + 2) * 4);
    size_t offSort   = offBcnt   + al((size_t)256 * 4);
    size_t total     = offSort   + al((size_t)NEtot * 8);

    char* ws = (char*)d_ws;
    unsigned short* Hbf    = (unsigned short*)(ws + offHbf);
    unsigned short* VfragG = (unsigned short*)(ws + offVfrag);
    unsigned short* Wfrag  = (unsigned short*)(ws + offWfrag);

    int n8  = Ne * DIM / 8;            // 1,600,000
    int nHb = (n8 + 255) / 256;        // 6250

    if (ws_size < total) {
        // fallback: atomic-scatter path (round 2)
        h_to_bf<<<nHb, 256, 0, stream>>>(H, Hbf, n8);
        build_wfrag<<<64, 256, 0, stream>>>(A, V, Wfrag);
        hipMemsetAsync(d_out, 0, (size_t)Ne * DIM * sizeof(float), stream);
        int blocks = 4096;
        int waves_per_rel = blocks * 4 / NR;
        int groups_per_rel = E / 16;
        rgcn_main<<<blocks, 256, 0, stream>>>(Hbf, Wfrag, erow, ecol, eval, out,
                                              E, groups_per_rel, waves_per_rel);
        return;
    }

    int2*           sorted1  = (int2*)(ws + offSort1);
    int*            rowStart = (int*)(ws + offRow);
    int*            bcnt     = (int*)(ws + offBcnt);
    int2*           sorted   = (int2*)(ws + offSort);

    // merged prologue: Hbf + VfragG + bcnt=0 in one dispatch
    prep_kernel<<<nHb + 32 + 1, 256, 0, stream>>>(H, Hbf, n8, V, VfragG,
                                                  bcnt, nHb);

    // two-level bucket sort (scan folded into pass 2)
    int sblocks = 1024;
    int chunk   = (NEtot + sblocks - 1) / sblocks;   // 1563
    bucket_scatter<<<sblocks, 256, 0, stream>>>(erow, ecol, eval, bcnt,
                                                sorted1, NEtot, E, chunk);
    bucket_sort<<<nbuc, 1024, 0, stream>>>(sorted1, bcnt, rowStart,
                                           sorted, Ne, nbuc);

    // FUSED aggregation + V-GEMM: persistent, 1 block/CU, 8-tile batches,
    // V from L2, AggT never touches HBM.
    fused_kernel<<<256, 1024, 0, stream>>>(Hbf, rowStart, sorted, A,
                                           VfragG, out, Ne, nTiles);
}

// Round 11
// 296.975 us; speedup vs baseline: 1.2566x; 1.2566x over previous
//
#include <hip/hip_runtime.h>

typedef __attribute__((ext_vector_type(8))) short short8;
typedef __attribute__((ext_vector_type(4))) float floatx4;
typedef __attribute__((ext_vector_type(2))) float floatx2;

constexpr int DIM   = 128;   // dim_in == dim_out
constexpr int NB    = 4;     // bases
constexpr int NR    = 8;     // relations
constexpr int BROWS = 512;   // rows per sort bucket
constexpr int BCAP  = 16384; // fixed bucket capacity (mean 8192, +90 sigma)

static __device__ __forceinline__ unsigned short f2bf(float f) {
    unsigned int u = __float_as_uint(f);
    u += 0x7FFFu + ((u >> 16) & 1u);
    return (unsigned short)(u >> 16);
}
static __device__ __forceinline__ float bf_lo(unsigned int h) {
    return __uint_as_float(h << 16);
}
static __device__ __forceinline__ float bf_hi(unsigned int h) {
    return __uint_as_float(h & 0xFFFF0000u);
}

// ---------------------------------------------------------------------------
// Vfrag[b][ot][ks][lane][j] = V[b][k][o], k=ks*32+(lane>>4)*8+j, o=ot*16+(lane&15)
// (fallback path; main path uses prep_kernel)
// ---------------------------------------------------------------------------
__global__ __launch_bounds__(256) void build_vfrag(
    const float* __restrict__ V, unsigned short* __restrict__ VfragG)
{
    int idx  = blockIdx.x * 256 + threadIdx.x;   // 0 .. 8191
    int lane = idx & 63;
    int ks   = (idx >> 6) & 3;
    int ot   = (idx >> 8) & 7;
    int b    = idx >> 11;

    int o  = ot * 16 + (lane & 15);
    int kb = ks * 32 + (lane >> 4) * 8;

    short8 v;
#pragma unroll
    for (int j = 0; j < 8; ++j)
        v[j] = (short)f2bf(V[((size_t)b * DIM + kb + j) * DIM + o]);
    *reinterpret_cast<short8*>(VfragG + (size_t)idx * 8) = v;
}

// ---------------------------------------------------------------------------
// W_r fragments (fallback path only)
// ---------------------------------------------------------------------------
__global__ __launch_bounds__(256) void build_wfrag(
    const float* __restrict__ A, const float* __restrict__ V,
    unsigned short* __restrict__ Wfrag)
{
    int idx  = blockIdx.x * 256 + threadIdx.x;   // 0 .. 16383
    int lane = idx & 63;
    int ks   = (idx >> 6) & 3;
    int ot   = (idx >> 8) & 7;
    int r    = idx >> 11;

    int o     = ot * 16 + (lane & 15);
    int kbase = ks * 32 + (lane >> 4) * 8;

    float a0 = A[r * NB + 0], a1 = A[r * NB + 1];
    float a2 = A[r * NB + 2], a3 = A[r * NB + 3];

    short8 v;
#pragma unroll
    for (int j = 0; j < 8; ++j) {
        int k = kbase + j;
        float w = a0 * V[(0 * DIM + k) * DIM + o]
                + a1 * V[(1 * DIM + k) * DIM + o]
                + a2 * V[(2 * DIM + k) * DIM + o]
                + a3 * V[(3 * DIM + k) * DIM + o];
        v[j] = (short)f2bf(w);
    }
    *reinterpret_cast<short8*>(Wfrag + (size_t)idx * 8) = v;
}

// ---------------------------------------------------------------------------
// H (fp32) -> Hbf (bf16)  (fallback path; main path uses prep_kernel)
// ---------------------------------------------------------------------------
__global__ __launch_bounds__(256) void h_to_bf(
    const float* __restrict__ H, unsigned short* __restrict__ Hbf, int n8)
{
    int i = blockIdx.x * 256 + threadIdx.x;
    if (i >= n8) return;
    const float4* hp = reinterpret_cast<const float4*>(H) + (size_t)i * 2;
    float4 f0 = hp[0];
    float4 f1 = hp[1];
    short8 v;
    v[0] = (short)f2bf(f0.x); v[1] = (short)f2bf(f0.y);
    v[2] = (short)f2bf(f0.z); v[3] = (short)f2bf(f0.w);
    v[4] = (short)f2bf(f1.x); v[5] = (short)f2bf(f1.y);
    v[6] = (short)f2bf(f1.z); v[7] = (short)f2bf(f1.w);
    *reinterpret_cast<short8*>(Hbf + (size_t)i * 8) = v;
}

// ---------------------------------------------------------------------------
// Merged prologue: h_to_bf + build_vfrag + bcnt zero in one dispatch.
// ---------------------------------------------------------------------------
__global__ __launch_bounds__(256) void prep_kernel(
    const float* __restrict__ H, unsigned short* __restrict__ Hbf, int n8,
    const float* __restrict__ V, unsigned short* __restrict__ VfragG,
    int* __restrict__ bcnt, int nHb)
{
    int blk = blockIdx.x;
    int t   = threadIdx.x;
    if (blk < nHb) {
        int i = blk * 256 + t;
        if (i >= n8) return;
        const float4* hp = reinterpret_cast<const float4*>(H) + (size_t)i * 2;
        float4 f0 = hp[0];
        float4 f1 = hp[1];
        short8 v;
        v[0] = (short)f2bf(f0.x); v[1] = (short)f2bf(f0.y);
        v[2] = (short)f2bf(f0.z); v[3] = (short)f2bf(f0.w);
        v[4] = (short)f2bf(f1.x); v[5] = (short)f2bf(f1.y);
        v[6] = (short)f2bf(f1.z); v[7] = (short)f2bf(f1.w);
        *reinterpret_cast<short8*>(Hbf + (size_t)i * 8) = v;
    } else if (blk < nHb + 32) {
        int idx  = (blk - nHb) * 256 + t;     // 0 .. 8191
        int lane = idx & 63;
        int ks   = (idx >> 6) & 3;
        int ot   = (idx >> 8) & 7;
        int b    = idx >> 11;
        int o  = ot * 16 + (lane & 15);
        int kb = ks * 32 + (lane >> 4) * 8;
        short8 v;
#pragma unroll
        for (int j = 0; j < 8; ++j)
            v[j] = (short)f2bf(V[((size_t)b * DIM + kb + j) * DIM + o]);
        *reinterpret_cast<short8*>(VfragG + (size_t)idx * 8) = v;
    } else {
        bcnt[t] = 0;
    }
}

// ---------------------------------------------------------------------------
// Sort pass 1: scatter edges into fixed-capacity coarse buckets.
// ---------------------------------------------------------------------------
__global__ __launch_bounds__(256) void bucket_scatter(
    const int* __restrict__ erow, const int* __restrict__ ecol,
    const float* __restrict__ eval, int* __restrict__ bcnt,
    int2* __restrict__ sorted1, int n, int E, int chunk)
{
    __shared__ int cnt[256];
    __shared__ int base[256];
    int t = threadIdx.x;
    cnt[t] = 0;
    __syncthreads();

    int s = blockIdx.x * chunk;
    int e = s + chunk; if (e > n) e = n;

    for (int i = s + t; i < e; i += 256)
        atomicAdd(&cnt[erow[i] >> 9], 1);
    __syncthreads();

    int c = cnt[t];
    base[t] = (c > 0) ? atomicAdd(&bcnt[t], c) : 0;
    cnt[t] = 0;
    __syncthreads();

    for (int i = s + t; i < e; i += 256) {
        int row = erow[i];
        int bkt = row >> 9;
        int rank = atomicAdd(&cnt[bkt], 1);
        int r = (int)((unsigned)i / (unsigned)E);
        int2 m;
        m.x = ((row & (BROWS - 1)) << 20) | (r << 17) | ecol[i];
        m.y = __float_as_int(eval[i]);
        sorted1[(size_t)bkt * BCAP + base[bkt] + rank] = m;
    }
}

// ---------------------------------------------------------------------------
// Sort pass 2: one block per bucket; compacts to exact final positions.
// ---------------------------------------------------------------------------
__global__ __launch_bounds__(1024) void bucket_sort(
    const int2* __restrict__ sorted1, const int* __restrict__ bcnt,
    int* __restrict__ rowStart, int2* __restrict__ sorted, int Ne, int nbuc)
{
    __shared__ int hcnt[BROWS];   // per-local-row counts, then rank counters
    __shared__ int hoff[BROWS];   // per-local-row exclusive offsets
    __shared__ int sd[256];       // bucket-count inclusive scan
    int b = blockIdx.x;
    int t = threadIdx.x;

    for (int i = t; i < BROWS; i += 1024) hcnt[i] = 0;

    if (t < 256) sd[t] = (t < nbuc) ? bcnt[t] : 0;
    __syncthreads();
#pragma unroll
    for (int off = 1; off < 256; off <<= 1) {
        int v = (t < 256 && t >= off) ? sd[t - off] : 0;
        __syncthreads();
        if (t < 256) sd[t] += v;
        __syncthreads();
    }
    if (b == 0 && t == nbuc - 1) rowStart[Ne] = sd[t];

    int n  = bcnt[b];
    int bs = sd[b] - n;               // exclusive prefix of this bucket
    const int2* src = sorted1 + (size_t)b * BCAP;

    for (int i = t; i < n; i += 1024)
        atomicAdd(&hcnt[(unsigned)src[i].x >> 20], 1);
    __syncthreads();

    // parallel exclusive scan of the 512 row counts
    if (t < BROWS) hoff[t] = hcnt[t];
    __syncthreads();
#pragma unroll
    for (int off = 1; off < BROWS; off <<= 1) {
        int v = (t < BROWS && t >= off) ? hoff[t - off] : 0;
        __syncthreads();
        if (t < BROWS) hoff[t] += v;
        __syncthreads();
    }
    if (t < BROWS) hoff[t] -= hcnt[t];   // own-element only: no hazard
    __syncthreads();

    int rs = b * BROWS;
    int nr = Ne - rs; if (nr > BROWS) nr = BROWS;
    for (int j = t; j < nr; j += 1024)
        rowStart[rs + j] = bs + hoff[j];

    for (int i = t; i < BROWS; i += 1024) hcnt[i] = 0;
    __syncthreads();

    for (int i = t; i < n; i += 1024) {
        int2 m = src[i];
        int lr = (unsigned)m.x >> 20;
        int pos = bs + hoff[lr] + atomicAdd(&hcnt[lr], 1);
        sorted[pos] = m;
    }
}

// ---------------------------------------------------------------------------
// FUSED K_A + K_B, round-9 structure (V in LDS — round-10's V-from-L2 leaked
// 106 MB of FETCH via gather-induced eviction + spilled) with three fixes:
//  * BATCH=2: ldsA[2] (32 KB) + ldsV (128 KB) = 163840 B = exactly the
//    160 KiB/CU LDS. Barrier imbalance max/mean: 1.59 -> 1.41.
//  * phase 2 = 16 tasks (2 tiles x 8 col-blocks) across ALL 16 waves
//    (round 9 idled 8 waves); one task/wave -> no load-hoist pressure.
//  * ldsA XOR swizzle (x-bit flip when ks-slot odd; mirrored on read):
//    ds_write 4-way/16-bank -> 2-way/32-bank (free). Round 10 verified the
//    mechanism (4M -> 800K conflicts).
// __launch_bounds__(1024, 4): 128-VGPR cap, 1 block/CU (proven round 9).
// ---------------------------------------------------------------------------
#define AGG_LOAD8(kk, vv, hh, base)                                          \
    _Pragma("unroll")                                                        \
    for (int u = 0; u < 8; ++u) {                                            \
        int2 m = sorted[(base) + u];                                         \
        kk[u] = __builtin_amdgcn_readfirstlane(m.x);                         \
        vv[u] = __uint_as_float(__builtin_amdgcn_readfirstlane(m.y));        \
    }                                                                        \
    _Pragma("unroll")                                                        \
    for (int u = 0; u < 8; ++u)                                              \
        hh[u] = reinterpret_cast<const unsigned int*>(                       \
            Hbf + (size_t)(kk[u] & 0x1FFFF) * DIM)[lane];

#define AGG_FMA8(kk, vv, hh)                                                 \
    _Pragma("unroll")                                                        \
    for (int u = 0; u < 8; ++u) {                                            \
        float4 a = Af[((unsigned)kk[u] >> 17) & 7];                          \
        floatx2 h; h[0] = bf_lo(hh[u]); h[1] = bf_hi(hh[u]);                 \
        float s0 = vv[u] * a.x, s1 = vv[u] * a.y;                            \
        float s2 = vv[u] * a.z, s3 = vv[u] * a.w;                            \
        acc[0] += (floatx2){s0, s0} * h;                                     \
        acc[1] += (floatx2){s1, s1} * h;                                     \
        acc[2] += (floatx2){s2, s2} * h;                                     \
        acc[3] += (floatx2){s3, s3} * h;                                     \
    }

__global__ __launch_bounds__(1024, 4) void fused_kernel(
    const unsigned short* __restrict__ Hbf,
    const int*  __restrict__ rowStart,
    const int2* __restrict__ sorted,
    const float* __restrict__ Aw,
    const unsigned short* __restrict__ VfragG,
    float* __restrict__ out, int Ne, int nTiles)
{
    __shared__ short8 ldsV[8192];               // full V-frag set, 128 KB
    __shared__ unsigned short ldsA[2][8192];    // two A-tiles, 32 KB

    int tid  = threadIdx.x;
    int wave = tid >> 6;
    int lane = tid & 63;
    int quad = lane >> 4, l15 = lane & 15;

    for (int i = tid; i < 8192; i += 1024)
        ldsV[i] = reinterpret_cast<const short8*>(VfragG)[i];
    // (first in-loop barrier covers ldsV readiness)

    const float4* Af = reinterpret_cast<const float4*>(Aw);

    // contiguous tile range for this block (differs by <=1 tile per block)
    int t0 = (int)(((long long)blockIdx.x       * nTiles) / gridDim.x);
    int t1 = (int)(((long long)(blockIdx.x + 1) * nTiles) / gridDim.x);

    // ldsA write slot (ushort units) for row 'wave', cols {2*lane,2*lane+1}
    // of each basis; x-bit XOR-swizzled when the ks-slot (writer quad) is odd
    int x_ = (lane >> 2) & 3, y_ = lane & 3;
    int awBase = (quad * 512 + wave * 32 + x_ * 8 + y_ * 2)
               ^ ((quad & 1) << 4);

    for (int base = t0; base < t1; base += 2) {
        int nsub = t1 - base; if (nsub > 2) nsub = 2;

        // ---- phase 1: aggregate row 'wave' of each sub-tile ----
        for (int sub = 0; sub < nsub; ++sub) {
            int node = (base + sub) * 16 + wave;
            floatx2 acc[4];
#pragma unroll
            for (int b = 0; b < 4; ++b) acc[b] = (floatx2){0.f, 0.f};

            if (node < Ne) {
                int s = __builtin_amdgcn_readfirstlane(rowStart[node]);
                int e = __builtin_amdgcn_readfirstlane(rowStart[node + 1]);
                int i = s;
                if (i + 8 <= e) {
                    int kkA[8], kkB[8];
                    float vvA[8], vvB[8];
                    unsigned int hhA[8], hhB[8];
                    AGG_LOAD8(kkA, vvA, hhA, i); i += 8;
                    for (;;) {
                        if (i + 8 <= e) {
                            AGG_LOAD8(kkB, vvB, hhB, i); i += 8;
                            AGG_FMA8(kkA, vvA, hhA);
                        } else { AGG_FMA8(kkA, vvA, hhA); break; }
                        if (i + 8 <= e) {
                            AGG_LOAD8(kkA, vvA, hhA, i); i += 8;
                            AGG_FMA8(kkB, vvB, hhB);
                        } else { AGG_FMA8(kkB, vvB, hhB); break; }
                    }
                }
                for (; i < e; ++i) {
                    int2 m = sorted[i];
                    int k = __builtin_amdgcn_readfirstlane(m.x);
                    float v = __uint_as_float(
                        __builtin_amdgcn_readfirstlane(m.y));
                    unsigned int hu = reinterpret_cast<const unsigned int*>(
                        Hbf + (size_t)(k & 0x1FFFF) * DIM)[lane];
                    float4 a = Af[((unsigned)k >> 17) & 7];
                    floatx2 h; h[0] = bf_lo(hu); h[1] = bf_hi(hu);
                    float s0 = v * a.x, s1 = v * a.y;
                    float s2 = v * a.z, s3 = v * a.w;
                    acc[0] += (floatx2){s0, s0} * h;
                    acc[1] += (floatx2){s1, s1} * h;
                    acc[2] += (floatx2){s2, s2} * h;
                    acc[3] += (floatx2){s3, s3} * h;
                }
            }
            unsigned short* aw = &ldsA[sub][0] + awBase;
#pragma unroll
            for (int b = 0; b < 4; ++b) {
                unsigned int pk = (unsigned int)f2bf(acc[b][0])
                                | ((unsigned int)f2bf(acc[b][1]) << 16);
                *reinterpret_cast<unsigned int*>(aw + b * 2048) = pk;
            }
        }
        __syncthreads();   // A-tiles complete (and ldsV on first iter)

        // ---- phase 2: 16 tasks (sub, ot), one per wave ----
        {
            int sub = wave >> 3, ot = wave & 7;
            if (sub < nsub) {
                const short8* a8 =
                    reinterpret_cast<const short8*>(&ldsA[sub][0]);
                floatx4 vacc = (floatx4){0.f, 0.f, 0.f, 0.f};
#pragma unroll
                for (int b = 0; b < 4; ++b)
#pragma unroll
                    for (int ks = 0; ks < 4; ++ks)
                        vacc = __builtin_amdgcn_mfma_f32_16x16x32_bf16(
                            ldsV[((b * 8 + ot) * 4 + ks) * 64 + lane],
                            a8[b * 256 + ks * 64 + l15 * 4
                               + (quad ^ ((ks & 1) << 1))],
                            vacc, 0, 0, 0);

                int onode = (base + sub) * 16 + l15;
                if (onode < Ne) {
                    float4 st;
                    st.x = vacc[0]; st.y = vacc[1];
                    st.z = vacc[2]; st.w = vacc[3];
                    *reinterpret_cast<float4*>(
                        out + (size_t)onode * DIM + ot * 16 + quad * 4) = st;
                }
            }
        }
        __syncthreads();   // protect ldsA before next batch
    }
}

// ---------------------------------------------------------------------------
// Fallback (ws too small): round-2 atomic kernel
// ---------------------------------------------------------------------------
__global__ __launch_bounds__(256) void rgcn_main(
    const unsigned short* __restrict__ Hbf,
    const unsigned short* __restrict__ Wfrag,
    const int*   __restrict__ erow,
    const int*   __restrict__ ecol,
    const float* __restrict__ eval,
    float*       __restrict__ out,
    int E, int groups_per_rel, int waves_per_rel)
{
    int wid  = blockIdx.x * 4 + (threadIdx.x >> 6);
    int lane = threadIdx.x & 63;
    int r    = wid & 7;
    int wr   = wid >> 3;
    int quad = lane >> 4;
    int l15  = lane & 15;

    short8 b[8][4];
    {
        const short8* wp = reinterpret_cast<const short8*>(
            Wfrag + (size_t)r * 16384);
#pragma unroll
        for (int ot = 0; ot < 8; ++ot)
#pragma unroll
            for (int ks = 0; ks < 4; ++ks)
                b[ot][ks] = wp[(ot * 4 + ks) * 64 + lane];
    }

    for (int g = wr; g < groups_per_rel; g += waves_per_rel) {
        int ebase = r * E + g * 16;
        int   colv = ecol[ebase + l15];
        int   rowv = erow[ebase + l15];
        float valv = eval[ebase + l15];

        short8 a[4];
        const unsigned short* hp = Hbf + (size_t)colv * DIM + quad * 8;
#pragma unroll
        for (int ks = 0; ks < 4; ++ks)
            a[ks] = *reinterpret_cast<const short8*>(hp + ks * 32);

        floatx4 acc[8];
#pragma unroll
        for (int ot = 0; ot < 8; ++ot) acc[ot] = (floatx4){0.f, 0.f, 0.f, 0.f};
#pragma unroll
        for (int ot = 0; ot < 8; ++ot)
#pragma unroll
            for (int ks = 0; ks < 4; ++ks)
                acc[ot] = __builtin_amdgcn_mfma_f32_16x16x32_bf16(
                    a[ks], b[ot][ks], acc[ot], 0, 0, 0);

        int   row4[4];
        float val4[4];
#pragma unroll
        for (int reg = 0; reg < 4; ++reg) {
            int src  = quad * 4 + reg;
            row4[reg] = __shfl(rowv, src, 64);
            val4[reg] = __shfl(valv, src, 64);
        }
#pragma unroll
        for (int ot = 0; ot < 8; ++ot)
#pragma unroll
            for (int reg = 0; reg < 4; ++reg) {
                float m = acc[ot][reg] * val4[reg];
                atomicAdd(out + (size_t)row4[reg] * DIM + ot * 16 + l15, m);
            }
    }
}

extern "C" void kernel_launch(void* const* d_in, const int* in_sizes, int n_in,
                              void* d_out, int out_size, void* d_ws, size_t ws_size,
                              hipStream_t stream)
{
    const float* H    = (const float*)d_in[0];
    const float* A    = (const float*)d_in[1];
    const float* V    = (const float*)d_in[2];
    const int*   erow = (const int*)d_in[3];
    const int*   ecol = (const int*)d_in[4];
    const float* eval = (const float*)d_in[5];
    float* out = (float*)d_out;

    int Ne    = in_sizes[0] / DIM;   // 100000
    int NEtot = in_sizes[3];         // 1.6M
    int E     = NEtot / NR;          // 200000

    auto al = [](size_t x) { return (x + 255) & ~(size_t)255; };

    int nbuc = (Ne + BROWS - 1) / BROWS;   // 196
    int nTiles = (Ne + 15) / 16;           // 6250 (Ne divisible by 16)

    size_t offHbf    = 0;
    size_t offVfrag  = offHbf    + al((size_t)Ne * DIM * 2);
    size_t offWfrag  = offVfrag  + al((size_t)8192 * 16);
    size_t offSort1  = offWfrag  + al((size_t)16384 * 16);
    size_t offRow    = offSort1  + al((size_t)nbuc * BCAP * 8);
    size_t offBcnt   = offRow    + al(((size_t)Ne + 2) * 4);
    size_t offSort   = offBcnt   + al((size_t)256 * 4);
    size_t total     = offSort   + al((size_t)NEtot * 8);

    char* ws = (char*)d_ws;
    unsigned short* Hbf    = (unsigned short*)(ws + offHbf);
    unsigned short* VfragG = (unsigned short*)(ws + offVfrag);
    unsigned short* Wfrag  = (unsigned short*)(ws + offWfrag);

    int n8  = Ne * DIM / 8;            // 1,600,000
    int nHb = (n8 + 255) / 256;        // 6250

    if (ws_size < total) {
        // fallback: atomic-scatter path (round 2)
        h_to_bf<<<nHb, 256, 0, stream>>>(H, Hbf, n8);
        build_wfrag<<<64, 256, 0, stream>>>(A, V, Wfrag);
        hipMemsetAsync(d_out, 0, (size_t)Ne * DIM * sizeof(float), stream);
        int blocks = 4096;
        int waves_per_rel = blocks * 4 / NR;
        int groups_per_rel = E / 16;
        rgcn_main<<<blocks, 256, 0, stream>>>(Hbf, Wfrag, erow, ecol, eval, out,
                                              E, groups_per_rel, waves_per_rel);
        return;
    }

    int2*           sorted1  = (int2*)(ws + offSort1);
    int*            rowStart = (int*)(ws + offRow);
    int*            bcnt     = (int*)(ws + offBcnt);
    int2*           sorted   = (int2*)(ws + offSort);

    // merged prologue: Hbf + VfragG + bcnt=0 in one dispatch
    prep_kernel<<<nHb + 32 + 1, 256, 0, stream>>>(H, Hbf, n8, V, VfragG,
                                                  bcnt, nHb);

    // two-level bucket sort (scan folded into pass 2)
    int sblocks = 1024;
    int chunk   = (NEtot + sblocks - 1) / sblocks;   // 1563
    bucket_scatter<<<sblocks, 256, 0, stream>>>(erow, ecol, eval, bcnt,
                                                sorted1, NEtot, E, chunk);
    bucket_sort<<<nbuc, 1024, 0, stream>>>(sorted1, bcnt, rowStart,
                                           sorted, Ne, nbuc);

    // FUSED aggregation + V-GEMM: persistent, 1 block/CU, 2-tile batches,
    // V in LDS, AggT never touches HBM.
    fused_kernel<<<256, 1024, 0, stream>>>(Hbf, rowStart, sorted, A,
                                           VfragG, out, Ne, nTiles);
}